// Round 1
// baseline (9216.778 us; speedup 1.0000x reference)
//
#include <hip/hip_runtime.h>
#include <stdint.h>

typedef unsigned short u16;
typedef __attribute__((ext_vector_type(8))) short short8;
typedef __attribute__((ext_vector_type(4))) float f32x4;

// ---------------- device-global blob (avoids any ws_size dependency) ----------------
#define SZ_BIGW    (4096ull*1024ull*2ull)          // one [4096x1024] bf16 matrix, fragment-tiled
#define OFF_WHH1   (0ull)
#define OFF_WIH2   (OFF_WHH1 + SZ_BIGW)
#define OFF_WHH2   (OFF_WIH2 + SZ_BIGW)
#define OFF_WIH3   (OFF_WHH2 + SZ_BIGW)
#define OFF_WHH3   (OFF_WIH3 + SZ_BIGW)
#define OFF_MCOMB  (OFF_WHH3 + SZ_BIGW)            // W_ih1 @ W_dec  [4096x1024]
#define OFF_WIH1   (OFF_MCOMB + SZ_BIGW)           // [4096 x 160(pad of 132)]
#define SZ_WIH1    (4096ull*160ull*2ull)
#define OFF_WDECF  (OFF_WIH1 + SZ_WIH1)            // W_dec as B-op, rows f (pad 160) x K=1024
#define SZ_WDECF   (160ull*1024ull*2ull)
#define OFF_WDECB  (OFF_WDECF + SZ_WDECF)          // W_dec^T as B-op, rows k(1024) x f(pad 160)
#define SZ_WDECB   (1024ull*160ull*2ull)
#define OFF_XPRIM  (OFF_WDECB + SZ_WDECB)          // initial_seq bf16 A-layout: [64 t][20 kc][32 b][8]
#define SZ_XPRIM   (64ull*5120ull*2ull)
#define OFF_H2HIST (OFF_XPRIM + SZ_XPRIM)          // 129 slots of h2 (A-layout), slot0 = prime63
#define SZ_H2HIST  (129ull*32768ull*2ull)
#define OFF_H0     (OFF_H2HIST + SZ_H2HIST)        // h buffers: 2 parities each
#define SZ_H       (32768ull*2ull)
#define OFF_H1     (OFF_H0 + 2ull*SZ_H)
#define OFF_H2     (OFF_H1 + 2ull*SZ_H)
#define OFF_C0     (OFF_H2 + 2ull*SZ_H)            // cell states fp32
#define SZ_C       (32768ull*4ull)
#define OFF_C1     (OFF_C0 + SZ_C)
#define OFF_C2     (OFF_C1 + SZ_C)
#define OFF_BS1    (OFF_C2 + SZ_C)                 // bias sums fp32 [4096]
#define OFF_BS1G   (OFF_BS1 + 16384ull)
#define OFF_BS2    (OFF_BS1G + 16384ull)
#define OFF_BS3    (OFF_BS2 + 16384ull)
#define BLOB_SIZE  (OFF_BS3 + 16384ull)

__device__ unsigned char g_blob[BLOB_SIZE];

// zero region: all h (6) + all c (3), contiguous
#define ZERO_BYTES (6ull*SZ_H + 3ull*SZ_C)   // 786432

__device__ __forceinline__ u16 f2bf(float f) {
  unsigned u = __float_as_uint(f);
  u += 0x7fffu + ((u >> 16) & 1u);
  return (u16)(u >> 16);
}
__device__ __forceinline__ float sigm(float x) { return 1.f / (1.f + __expf(-x)); }
__device__ __forceinline__ float tanh_(float x) {
  x = fminf(fmaxf(x, -40.f), 40.f);
  float e = __expf(2.f * x);
  return (e - 1.f) / (e + 1.f);
}

// ---------------- prep kernels ----------------
__global__ __launch_bounds__(256) void k_zero(uint4* p, int n) {
  int i = blockIdx.x * 256 + threadIdx.x;
  for (; i < n; i += gridDim.x * 256) p[i] = make_uint4(0u, 0u, 0u, 0u);
}

// fragment-tiled B/A layout: idx(j,k) = ((j>>4)*(Kpad>>3) + (k>>3))*128 + (j&15)*8 + (k&7)
__global__ __launch_bounds__(256) void k_swizzle(const float* __restrict__ src, u16* __restrict__ dst,
                                                 int J, int Jsrc, int Kpad, int Ksrc, int srcld, int transposed) {
  int total = J * Kpad;
  int nkc = Kpad >> 3;
  for (int o = blockIdx.x * 256 + threadIdx.x; o < total; o += gridDim.x * 256) {
    int chunk = o >> 7, within = o & 127;
    int nt = chunk / nkc, kc = chunk - nt * nkc;
    int jr = within >> 3, ke = within & 7;
    int j = nt * 16 + jr, k = kc * 8 + ke;
    float v = 0.f;
    if (j < Jsrc && k < Ksrc)
      v = transposed ? src[(size_t)k * srcld + j] : src[(size_t)j * srcld + k];
    dst[o] = f2bf(v);
  }
}

// initial_seq [32][64][132] fp32 -> per-t A-layout bf16 [64][20 kc][32 b][8], k padded to 160
__global__ __launch_bounds__(256) void k_xprim(const float* __restrict__ iseq, u16* __restrict__ dst) {
  int o = blockIdx.x * 256 + threadIdx.x;
  if (o >= 64 * 5120) return;
  int t = o / 5120, rem = o - t * 5120;
  int kc = rem >> 8, b = (rem >> 3) & 31, ke = rem & 7;
  int k = kc * 8 + ke;
  float v = (k < 132) ? iseq[(size_t)b * (64 * 132) + t * 132 + k] : 0.f;
  dst[o] = f2bf(v);
}

__global__ __launch_bounds__(256) void k_bias(const float* bih1, const float* bhh1,
                                              const float* bih2, const float* bhh2,
                                              const float* bih3, const float* bhh3,
                                              const float* __restrict__ Wih1, const float* __restrict__ bdec,
                                              float* bs1, float* bs1g, float* bs2, float* bs3) {
  int j = blockIdx.x * 256 + threadIdx.x;
  if (j >= 4096) return;
  float s1 = bih1[j] + bhh1[j];
  float bc = 0.f;
  const float* wr = Wih1 + (size_t)j * 132;
  for (int f = 0; f < 132; ++f) bc += wr[f] * bdec[f];
  bs1[j] = s1;
  bs1g[j] = s1 + bc;   // folded decoder bias contribution for generation phase
  bs2[j] = bih2[j] + bhh2[j];
  bs3[j] = bih3[j] + bhh3[j];
}

// Mcomb[j][k] = sum_f Wih1[j][f]*Wdec[f][k]; A = Wih1 tiled (K=160), B = WdecB (rows k, K=160)
// output written in B-op fragment layout (rows j=4096, K=1024)
__global__ __launch_bounds__(256) void k_mcomb(const u16* __restrict__ A, const u16* __restrict__ Bm,
                                               u16* __restrict__ dst) {
  int blk = blockIdx.x;                   // 4096 = 256 mt x 16 jg
  int mt = blk & 255, jg = blk >> 8;
  int w = threadIdx.x >> 6, l = threadIdx.x & 63, q = l >> 4, r = l & 15;
  int nt = jg * 4 + w;                    // 0..63 over N=1024
  f32x4 acc = {};
  for (int ks = 0; ks < 5; ++ks) {
    short8 a = *(const short8*)(A + ((size_t)mt * 20 + ks * 4 + q) * 128 + r * 8);
    short8 b = *(const short8*)(Bm + ((size_t)nt * 20 + ks * 4 + q) * 128 + r * 8);
    acc = __builtin_amdgcn_mfma_f32_16x16x32_bf16(a, b, acc, 0, 0, 0);
  }
  // C: row=(q*4+i) -> j = mt*16+row ; col=r -> kout = nt*16+r
  int kout = nt * 16 + r;
#pragma unroll
  for (int i = 0; i < 4; ++i) {
    int jrow = q * 4 + i;  // j&15 ; j>>4 == mt
    dst[(((size_t)mt * 128 + (kout >> 3)) << 7) + jrow * 8 + (kout & 7)] = f2bf(acc[i]);
  }
}

// ---------------- fused LSTM layer: gates GEMM (2 segments) + cell update ----------------
// grid 64 (h-tile of 16), 256 threads = 4 waves (4-way K-split)
// wave: 2 M-tiles (batch 32) x 4 gate N-tiles -> 8 MFMAs/k-step
__global__ __launch_bounds__(256) void k_layer(const u16* __restrict__ xa, const u16* __restrict__ Wa, int nka,
                                               const u16* __restrict__ xb, const u16* __restrict__ Wb, int nkb,
                                               const float* __restrict__ bsum, float* __restrict__ c,
                                               u16* __restrict__ hout) {
  int ht = blockIdx.x;
  int w = threadIdx.x >> 6, l = threadIdx.x & 63, q = l >> 4, r = l & 15;
  f32x4 acc[4][2] = {};
  int nkca = nka * 4, nkcb = nkb * 4;

  for (int ks = w; ks < nka; ks += 4) {
    const u16* xp = xa + ks * 1024 + q * 256 + r * 8;
    short8 a0 = *(const short8*)(xp);
    short8 a1 = *(const short8*)(xp + 128);
#pragma unroll
    for (int g = 0; g < 4; ++g) {
      short8 bf = *(const short8*)(Wa + (((size_t)(g * 64 + ht) * nkca + ks * 4) << 7) + l * 8);
      acc[g][0] = __builtin_amdgcn_mfma_f32_16x16x32_bf16(a0, bf, acc[g][0], 0, 0, 0);
      acc[g][1] = __builtin_amdgcn_mfma_f32_16x16x32_bf16(a1, bf, acc[g][1], 0, 0, 0);
    }
  }
  for (int ks = w; ks < nkb; ks += 4) {
    const u16* xp = xb + ks * 1024 + q * 256 + r * 8;
    short8 a0 = *(const short8*)(xp);
    short8 a1 = *(const short8*)(xp + 128);
#pragma unroll
    for (int g = 0; g < 4; ++g) {
      short8 bf = *(const short8*)(Wb + (((size_t)(g * 64 + ht) * nkcb + ks * 4) << 7) + l * 8);
      acc[g][0] = __builtin_amdgcn_mfma_f32_16x16x32_bf16(a0, bf, acc[g][0], 0, 0, 0);
      acc[g][1] = __builtin_amdgcn_mfma_f32_16x16x32_bf16(a1, bf, acc[g][1], 0, 0, 0);
    }
  }

  __shared__ float red[4][4][2][256];
#pragma unroll
  for (int g = 0; g < 4; ++g)
#pragma unroll
    for (int mt = 0; mt < 2; ++mt)
#pragma unroll
      for (int i = 0; i < 4; ++i) red[w][g][mt][l * 4 + i] = acc[g][mt][i];
  __syncthreads();

  for (int pp = threadIdx.x; pp < 512; pp += 256) {
    int b = pp >> 4, hs = pp & 15;
    int mt = b >> 4, row = b & 15;
    int lidx = ((row >> 2) * 16 + hs) * 4 + (row & 3);
    int j0 = ht * 16 + hs;
    float gi = red[0][0][mt][lidx] + red[1][0][mt][lidx] + red[2][0][mt][lidx] + red[3][0][mt][lidx] + bsum[j0];
    float gf = red[0][1][mt][lidx] + red[1][1][mt][lidx] + red[2][1][mt][lidx] + red[3][1][mt][lidx] + bsum[1024 + j0];
    float gg = red[0][2][mt][lidx] + red[1][2][mt][lidx] + red[2][2][mt][lidx] + red[3][2][mt][lidx] + bsum[2048 + j0];
    float go = red[0][3][mt][lidx] + red[1][3][mt][lidx] + red[2][3][mt][lidx] + red[3][3][mt][lidx] + bsum[3072 + j0];
    float iv = sigm(gi), fv = sigm(gf), gv = tanh_(gg), ov = sigm(go);
    float cn = fv * c[b * 1024 + j0] + iv * gv;
    c[b * 1024 + j0] = cn;
    float hv = ov * tanh_(cn);
    hout[(j0 >> 3) * 256 + b * 8 + (j0 & 7)] = f2bf(hv);   // A-fragment layout for next consumer
  }
}

// ---------------- batched decoder over all 128 generated h2 states ----------------
// grid 1280 = 128 slots x 10 f-tiles, 256 thr = 4 waves (K-split over K=1024)
__global__ __launch_bounds__(256) void k_dec(const u16* __restrict__ h2hist, const u16* __restrict__ Wd,
                                             const float* __restrict__ bdec, float* __restrict__ out) {
  int blk = blockIdx.x;
  int s = blk / 10, nt = blk - s * 10;
  const u16* x = h2hist + (size_t)(s + 1) * 32768;
  int w = threadIdx.x >> 6, l = threadIdx.x & 63, q = l >> 4, r = l & 15;
  f32x4 acc[2] = {};
  for (int ks = w; ks < 32; ks += 4) {
    const u16* xp = x + ks * 1024 + q * 256 + r * 8;
    short8 a0 = *(const short8*)(xp);
    short8 a1 = *(const short8*)(xp + 128);
    short8 bf = *(const short8*)(Wd + (((size_t)nt * 128 + ks * 4) << 7) + l * 8);
    acc[0] = __builtin_amdgcn_mfma_f32_16x16x32_bf16(a0, bf, acc[0], 0, 0, 0);
    acc[1] = __builtin_amdgcn_mfma_f32_16x16x32_bf16(a1, bf, acc[1], 0, 0, 0);
  }
  __shared__ float red[4][2][256];
#pragma unroll
  for (int mt = 0; mt < 2; ++mt)
#pragma unroll
    for (int i = 0; i < 4; ++i) red[w][mt][l * 4 + i] = acc[mt][i];
  __syncthreads();
  for (int pp = threadIdx.x; pp < 512; pp += 256) {
    int b = pp >> 4, fs = pp & 15;
    int mt = b >> 4, row = b & 15;
    int lidx = ((row >> 2) * 16 + fs) * 4 + (row & 3);
    int f = nt * 16 + fs;
    if (f < 132) {
      float v = red[0][mt][lidx] + red[1][mt][lidx] + red[2][mt][lidx] + red[3][mt][lidx] + bdec[f];
      out[(size_t)b * (128 * 132) + s * 132 + f] = v;
    }
  }
}

// ---------------- host ----------------
extern "C" void kernel_launch(void* const* d_in, const int* in_sizes, int n_in,
                              void* d_out, int out_size, void* d_ws, size_t ws_size,
                              hipStream_t stream) {
  unsigned char* blob = nullptr;
  hipGetSymbolAddress((void**)&blob, HIP_SYMBOL(g_blob));

  const float* iseq = (const float*)d_in[0];
  const float* Wih1 = (const float*)d_in[2];
  const float* Whh1 = (const float*)d_in[3];
  const float* bih1 = (const float*)d_in[4];
  const float* bhh1 = (const float*)d_in[5];
  const float* Wih2 = (const float*)d_in[6];
  const float* Whh2 = (const float*)d_in[7];
  const float* bih2 = (const float*)d_in[8];
  const float* bhh2 = (const float*)d_in[9];
  const float* Wih3 = (const float*)d_in[10];
  const float* Whh3 = (const float*)d_in[11];
  const float* bih3 = (const float*)d_in[12];
  const float* bhh3 = (const float*)d_in[13];
  const float* Wdec = (const float*)d_in[14];
  const float* bdec = (const float*)d_in[15];

  u16* tWHH1 = (u16*)(blob + OFF_WHH1);
  u16* tWIH2 = (u16*)(blob + OFF_WIH2);
  u16* tWHH2 = (u16*)(blob + OFF_WHH2);
  u16* tWIH3 = (u16*)(blob + OFF_WIH3);
  u16* tWHH3 = (u16*)(blob + OFF_WHH3);
  u16* tMCOMB = (u16*)(blob + OFF_MCOMB);
  u16* tWIH1 = (u16*)(blob + OFF_WIH1);
  u16* tWDECF = (u16*)(blob + OFF_WDECF);
  u16* tWDECB = (u16*)(blob + OFF_WDECB);
  u16* XPRIM = (u16*)(blob + OFF_XPRIM);
  u16* H2HIST = (u16*)(blob + OFF_H2HIST);
  u16* H0[2] = {(u16*)(blob + OFF_H0), (u16*)(blob + OFF_H0) + 32768};
  u16* H1[2] = {(u16*)(blob + OFF_H1), (u16*)(blob + OFF_H1) + 32768};
  u16* H2[2] = {(u16*)(blob + OFF_H2), (u16*)(blob + OFF_H2) + 32768};
  float* C0 = (float*)(blob + OFF_C0);
  float* C1 = (float*)(blob + OFF_C1);
  float* C2 = (float*)(blob + OFF_C2);
  float* BS1 = (float*)(blob + OFF_BS1);
  float* BS1G = (float*)(blob + OFF_BS1G);
  float* BS2 = (float*)(blob + OFF_BS2);
  float* BS3 = (float*)(blob + OFF_BS3);

  // prep
  k_zero<<<192, 256, 0, stream>>>((uint4*)(blob + OFF_H0), (int)(ZERO_BYTES / 16));
  k_swizzle<<<2048, 256, 0, stream>>>(Whh1, tWHH1, 4096, 4096, 1024, 1024, 1024, 0);
  k_swizzle<<<2048, 256, 0, stream>>>(Wih2, tWIH2, 4096, 4096, 1024, 1024, 1024, 0);
  k_swizzle<<<2048, 256, 0, stream>>>(Whh2, tWHH2, 4096, 4096, 1024, 1024, 1024, 0);
  k_swizzle<<<2048, 256, 0, stream>>>(Wih3, tWIH3, 4096, 4096, 1024, 1024, 1024, 0);
  k_swizzle<<<2048, 256, 0, stream>>>(Whh3, tWHH3, 4096, 4096, 1024, 1024, 1024, 0);
  k_swizzle<<<2048, 256, 0, stream>>>(Wih1, tWIH1, 4096, 4096, 160, 132, 132, 0);
  k_swizzle<<<512, 256, 0, stream>>>(Wdec, tWDECF, 160, 132, 1024, 1024, 1024, 0);
  k_swizzle<<<512, 256, 0, stream>>>(Wdec, tWDECB, 1024, 1024, 160, 132, 1024, 1);
  k_xprim<<<1280, 256, 0, stream>>>(iseq, XPRIM);
  k_bias<<<16, 256, 0, stream>>>(bih1, bhh1, bih2, bhh2, bih3, bhh3, Wih1, bdec, BS1, BS1G, BS2, BS3);
  k_mcomb<<<4096, 256, 0, stream>>>(tWIH1, tWDECB, tMCOMB);

  int p = 0;
  // priming: layer1 input from precomputed frames (K=160 pad), no decoder needed except h2 capture at t=63
  for (int t = 0; t < 64; ++t) {
    k_layer<<<64, 256, 0, stream>>>(XPRIM + t * 5120, tWIH1, 5, H0[p], tWHH1, 32, BS1, C0, H0[p ^ 1]);
    k_layer<<<64, 256, 0, stream>>>(H0[p ^ 1], tWIH2, 32, H1[p], tWHH2, 32, BS2, C1, H1[p ^ 1]);
    u16* h2out = (t == 63) ? H2HIST : H2[p ^ 1];
    k_layer<<<64, 256, 0, stream>>>(H1[p ^ 1], tWIH3, 32, H2[p], tWHH3, 32, BS3, C2, h2out);
    p ^= 1;
  }
  // generation: decoder folded into layer1 via Mcomb = Wih1 @ Wdec (and bias via BS1G)
  for (int n = 0; n < 128; ++n) {
    k_layer<<<64, 256, 0, stream>>>(H2HIST + (size_t)n * 32768, tMCOMB, 32, H0[p], tWHH1, 32, BS1G, C0, H0[p ^ 1]);
    k_layer<<<64, 256, 0, stream>>>(H0[p ^ 1], tWIH2, 32, H1[p], tWHH2, 32, BS2, C1, H1[p ^ 1]);
    k_layer<<<64, 256, 0, stream>>>(H1[p ^ 1], tWIH3, 32, H2HIST + (size_t)n * 32768, tWHH3, 32, BS3, C2,
                                    H2HIST + (size_t)(n + 1) * 32768);
    p ^= 1;
  }
  // one batched decoder over all 128 generated h2 states -> d_out fp32 [32][128][132]
  k_dec<<<1280, 256, 0, stream>>>(H2HIST, tWDECF, bdec, (float*)d_out);
}